// Round 9
// baseline (219.451 us; speedup 1.0000x reference)
//
#include <hip/hip_runtime.h>
#include <stdint.h>

#define HID 1024
#define SEQ 2048
#define NB 2
#define NH 16
#define HD 64
#define MROWS 4096  // NB*SEQ

typedef float f32x4 __attribute__((ext_vector_type(4)));
typedef short s16x4 __attribute__((ext_vector_type(4)));
typedef short s16x8 __attribute__((ext_vector_type(8)));
typedef uint32_t u32x4 __attribute__((ext_vector_type(4)));

#define MFMA16(a, b, c) __builtin_amdgcn_mfma_f32_16x16x32_bf16((a), (b), (c), 0, 0, 0)

#define GLOAD_LDS16(gp, lp)                                                    \
  __builtin_amdgcn_global_load_lds(                                            \
      (const __attribute__((address_space(1))) unsigned int*)(gp),             \
      (__attribute__((address_space(3))) unsigned int*)(lp), 16, 0, 0)

__device__ __forceinline__ short f2bf(float x) {
  uint32_t u = __builtin_bit_cast(uint32_t, x);
  u += 0x7fffu + ((u >> 16) & 1u);
  return (short)(u >> 16);
}

__device__ __forceinline__ uint32_t cvtpk(float lo, float hi) {
  uint32_t r;
  asm("v_cvt_pk_bf16_f32 %0, %1, %2" : "=v"(r) : "v"(lo), "v"(hi));
  return r;
}

// -------- merged prep: z<4 -> transpose-cast W_z; z==4 -> cast X --------
__global__ __launch_bounds__(256) void prep_kernel(
    const float* __restrict__ X, const float* __restrict__ w0,
    const float* __restrict__ w1, const float* __restrict__ w2,
    const float* __restrict__ w3, short* __restrict__ Xb,
    short* __restrict__ Wtall) {
  const int z = blockIdx.z;
  if (z == 4) {  // cast X: 1024 blocks x 16 elems/thread
    const size_t i = ((size_t)blockIdx.y * 32 + blockIdx.x) * 256 + threadIdx.x;
    const float* s = X + i * 16;
    short* d = Xb + i * 16;
#pragma unroll
    for (int h = 0; h < 2; h++) {
      f32x4 a = *(const f32x4*)(s + h * 8);
      f32x4 b = *(const f32x4*)(s + h * 8 + 4);
      s16x8 o;
      o[0] = f2bf(a[0]); o[1] = f2bf(a[1]); o[2] = f2bf(a[2]); o[3] = f2bf(a[3]);
      o[4] = f2bf(b[0]); o[5] = f2bf(b[1]); o[6] = f2bf(b[2]); o[7] = f2bf(b[3]);
      *(s16x8*)(d + h * 8) = o;
    }
    return;
  }
  __shared__ float t[32][33];
  const float* src = (z == 0) ? w0 : (z == 1) ? w1 : (z == 2) ? w2 : w3;
  short* dst = Wtall + ((size_t)z << 20);
  const int tx = threadIdx.x & 31, ty = threadIdx.x >> 5;
  const int r0 = blockIdx.y * 32, c0 = blockIdx.x * 32;
#pragma unroll
  for (int i = 0; i < 4; i++)
    t[ty + i * 8][tx] = src[(size_t)(r0 + ty + i * 8) * HID + c0 + tx];
  __syncthreads();
#pragma unroll
  for (int i = 0; i < 4; i++)
    dst[(size_t)(c0 + ty + i * 8) * HID + r0 + tx] = f2bf(t[tx][ty + i * 8]);
}

// ---------------- bf16 GEMM: C = A[M][1024] * Bt[N][1024]^T ----------------
// Tile (32*MI)x128, BK=32, 4 waves (2x2), 16x16x32 MFMA.
// Double-buffered LDS via global_load_lds + counted vmcnt:
// stage(next) -> vmcnt(NLD) -> barrier -> compute(cur) -> barrier.
// EPI 0 (MI=4): QKV epilogue: bias + scatter; Q pre-scaled by 0.125*log2(e).
// EPI 1: proj epilogue (bias + f32 out [m][1024])
template <int EPI, int MI>
__global__ __launch_bounds__(256) void gemm_bf16(
    const short* __restrict__ A, const short* __restrict__ Bt,
    const float* __restrict__ b0, const float* __restrict__ b1,
    const float* __restrict__ b2, short* __restrict__ Qb, short* __restrict__ Kg,
    short* __restrict__ Vg, float* __restrict__ Out) {
  __shared__ char lds[2][MI * 2048 + 8192];  // dbuf x (A [32*MI][32], B [128][32])
  const int tid = threadIdx.x;
  const int w = tid >> 6, l = tid & 63, lg = l >> 4, ln = l & 15;
  const int wm = w >> 1, wn = w & 1;
  const int m0 = blockIdx.y * (32 * MI), n0 = blockIdx.x * 128;

  f32x4 acc[MI][4];
#pragma unroll
  for (int i = 0; i < MI; i++)
#pragma unroll
    for (int j = 0; j < 4; j++) acc[i][j] = f32x4{0.f, 0.f, 0.f, 0.f};

  auto stage = [&](int buf, int k0) {
#pragma unroll
    for (int i = 0; i < MI / 2; i++) {  // A: MI*128 16B-chunks
      const int c = i * 256 + tid;
      const int row = c >> 2;
      const int cs = (c & 3) ^ (row & 3);  // source-side XOR swizzle
      GLOAD_LDS16(A + (size_t)(m0 + row) * 1024 + k0 + cs * 8,
                  lds[buf] + c * 16);
    }
#pragma unroll
    for (int i = 0; i < 2; i++) {  // B: 512 chunks
      const int c = i * 256 + tid;
      const int row = c >> 2;
      const int cs = (c & 3) ^ (row & 3);
      GLOAD_LDS16(Bt + (size_t)(n0 + row) * 1024 + k0 + cs * 8,
                  lds[buf] + MI * 2048 + c * 16);
    }
  };

  stage(0, 0);
  for (int kt = 0; kt < 32; ++kt) {
    const int cur = kt & 1;
    if (kt < 31) {
      stage(cur ^ 1, (kt + 1) * 32);  // next tile's loads stay in flight
      if constexpr (MI == 4)
        asm volatile("s_waitcnt vmcnt(4)" ::: "memory");
      else
        asm volatile("s_waitcnt vmcnt(3)" ::: "memory");
    } else {
      asm volatile("s_waitcnt vmcnt(0)" ::: "memory");
    }
    __builtin_amdgcn_s_barrier();  // cur tile resident for all waves
    __builtin_amdgcn_sched_barrier(0);

    const char* ldsc = lds[cur];
    s16x8 af[MI], bfr[4];
#pragma unroll
    for (int mi = 0; mi < MI; mi++) {
      const int row = wm * (16 * MI) + mi * 16 + ln;
      af[mi] = *(const s16x8*)(ldsc + row * 64 + ((lg ^ (row & 3)) * 16));
    }
#pragma unroll
    for (int ni = 0; ni < 4; ni++) {
      const int row = wn * 64 + ni * 16 + ln;
      bfr[ni] =
          *(const s16x8*)(ldsc + MI * 2048 + row * 64 + ((lg ^ (row & 3)) * 16));
    }
#pragma unroll
    for (int mi = 0; mi < MI; mi++)
#pragma unroll
      for (int ni = 0; ni < 4; ni++)
        acc[mi][ni] = MFMA16(af[mi], bfr[ni], acc[mi][ni]);

    __builtin_amdgcn_s_barrier();  // all reads done before next overwrite
    __builtin_amdgcn_sched_barrier(0);
  }

  // epilogue: C/D layout row=(lane>>4)*4+reg, col=lane&15
  const float QSC = 0.18033688011112042f;  // (1/8) * log2(e)
#pragma unroll
  for (int ni = 0; ni < 4; ni++) {
    const int c = n0 + wn * 64 + ni * 16 + ln;
    if (EPI == 0) {
      const int mat = c >> 10, cc = c & 1023, hh = cc >> 6, d = cc & 63;
      const float* bp = (mat == 0) ? b0 : (mat == 1) ? b1 : b2;
      const float bias = bp[cc];
#pragma unroll
      for (int mi = 0; mi < MI; mi++) {
#pragma unroll
        for (int r = 0; r < 4; r++) {
          const int m = m0 + wm * (16 * MI) + mi * 16 + lg * 4 + r;
          const int bb = m >> 11, s = m & 2047;
          const float fv = acc[mi][ni][r] + bias;
          const size_t bh = (size_t)(bb * 16 + hh);
          if (mat == 0) {
            Qb[(bh * SEQ + s) * HD + d] = f2bf(fv * QSC);  // pre-scaled Q
          } else if (mat == 1) {
            const int tile = s >> 6, rr = s & 63;
            Kg[bh * (SEQ * HD) + tile * 4096 + rr * 64 +
               ((((d >> 3) ^ (rr & 7)) << 3) | (d & 7))] = f2bf(fv);
          } else {
            // kappa-permute s within its 32-group (PV frag key order):
            const int sp = (s & ~31) | ((s & 12) << 1) | (((s >> 4) & 1) << 2) |
                           (s & 3);
            const int tile = sp >> 6, kp = sp & 63;
            Vg[bh * (SEQ * HD) + tile * 4096 + d * 64 +
               ((((kp >> 3) ^ (d & 7)) << 3) | (kp & 7))] = f2bf(fv);
          }
        }
      }
    } else {
      const float bias = b0[c];
#pragma unroll
      for (int mi = 0; mi < MI; mi++)
#pragma unroll
        for (int r = 0; r < 4; r++) {
          const int m = m0 + wm * (16 * MI) + mi * 16 + lg * 4 + r;
          Out[(size_t)m * 1024 + c] = acc[mi][ni][r] + bias;
        }
    }
  }
}

// ------------- flash attention (causal), 3-deep LDS pipeline -------------
// 512 blocks (XCD-swizzled), 4 waves/block, 64-row Q group. TRIPLE-buffered
// K/V LDS (3x16KB): stage(t+1) overwrites buf[(t-2)%3], already protected by
// the previous iteration's barrier -> ONE barrier + one vmcnt(4) per tile
// (vmcnt BEFORE barrier = cross-wave completion guarantee). Static ds_read
// offsets via compute_tile<BUF> (2 per-lane addr regs, all else immediate).
// VALU diet: Q pre-scaled (exp2-direct), defer-max, ones-MFMA psum, cvt_pk.

__device__ __forceinline__ void stage_tile(const short* Kt, const short* Vt,
                                           int t, char* sdst, int bufoff, int w) {
  const char* src = (w < 2) ? ((const char*)(Kt + (size_t)t * 4096) + (w & 1) * 4096)
                            : ((const char*)(Vt + (size_t)t * 4096) + (w & 1) * 4096);
  char* dst = sdst + bufoff;
#pragma unroll
  for (int j = 0; j < 4; j++)
    GLOAD_LDS16(src + j * 1024 + ((threadIdx.x & 63) * 16), dst + j * 1024);
}

template <int BUF, bool MASK>
__device__ __forceinline__ void compute_tile(const char* pA, const char* pB,
                                             const s16x8& qf0, const s16x8& qf1,
                                             const s16x8& ones, int k0, int qrow,
                                             int lg, float& m2, float& l_run,
                                             f32x4 o[4]) {
  f32x4 st[4];
  __builtin_amdgcn_s_setprio(1);
#pragma unroll
  for (int mt = 0; mt < 4; mt++) {
    const s16x8 k0f = *(const s16x8*)(pA + BUF + mt * 2048);
    const s16x8 k1f = *(const s16x8*)(pB + BUF + mt * 2048);
    st[mt] = f32x4{0.f, 0.f, 0.f, 0.f};
    st[mt] = MFMA16(k0f, qf0, st[mt]);
    st[mt] = MFMA16(k1f, qf1, st[mt]);
  }
  __builtin_amdgcn_s_setprio(0);
  // V frags (independent of softmax; latency hides under it)
  s16x8 vf[2][4];
#pragma unroll
  for (int vmt = 0; vmt < 4; vmt++) {
    vf[0][vmt] = *(const s16x8*)(pA + BUF + 8192 + vmt * 2048);
    vf[1][vmt] = *(const s16x8*)(pB + BUF + 8192 + vmt * 2048);
  }
  if (MASK) {
#pragma unroll
    for (int mt = 0; mt < 4; mt++)
#pragma unroll
      for (int r = 0; r < 4; r++) {
        const int key = k0 + mt * 16 + lg * 4 + r;
        if (key > qrow) st[mt][r] = -3e38f;
      }
  }
  // max via fused max3 chain
  float pmax = fmaxf(fmaxf(st[0][0], st[0][1]), st[0][2]);
  pmax = fmaxf(fmaxf(pmax, st[0][3]), st[1][0]);
  pmax = fmaxf(fmaxf(pmax, st[1][1]), st[1][2]);
  pmax = fmaxf(fmaxf(pmax, st[1][3]), st[2][0]);
  pmax = fmaxf(fmaxf(pmax, st[2][1]), st[2][2]);
  pmax = fmaxf(fmaxf(pmax, st[2][3]), st[3][0]);
  pmax = fmaxf(fmaxf(pmax, st[3][1]), st[3][2]);
  pmax = fmaxf(pmax, st[3][3]);

  if (!__all(pmax <= m2 + 8.0f)) {  // defer-max: rescale only on real growth
    pmax = fmaxf(pmax, __shfl_xor(pmax, 16));
    pmax = fmaxf(pmax, __shfl_xor(pmax, 32));
    const float m_new = fmaxf(m2, pmax);
    const float corr = exp2f(m2 - m_new);
    l_run *= corr;
#pragma unroll
    for (int i = 0; i < 4; i++) o[i] *= corr;
    m2 = m_new;
  }
#pragma unroll
  for (int mt = 0; mt < 4; mt++)
#pragma unroll
    for (int r = 0; r < 4; r++) st[mt][r] = exp2f(st[mt][r] - m2);

  s16x8 pf[2];
#pragma unroll
  for (int s = 0; s < 2; s++) {
    u32x4 wv;
    wv[0] = cvtpk(st[s * 2][0], st[s * 2][1]);
    wv[1] = cvtpk(st[s * 2][2], st[s * 2][3]);
    wv[2] = cvtpk(st[s * 2 + 1][0], st[s * 2 + 1][1]);
    wv[3] = cvtpk(st[s * 2 + 1][2], st[s * 2 + 1][3]);
    pf[s] = __builtin_bit_cast(s16x8, wv);
  }
  __builtin_amdgcn_s_setprio(1);
  f32x4 ps = f32x4{0.f, 0.f, 0.f, 0.f};
  ps = MFMA16(ones, pf[0], ps);
  ps = MFMA16(ones, pf[1], ps);
#pragma unroll
  for (int s = 0; s < 2; s++)
#pragma unroll
    for (int vmt = 0; vmt < 4; vmt++)
      o[vmt] = MFMA16(vf[s][vmt], pf[s], o[vmt]);
  __builtin_amdgcn_s_setprio(0);
  l_run += ps[0];
}

#define CT(BUF, MASKV, K0)                                                     \
  compute_tile<BUF, MASKV>(pA, pB, qf0, qf1, ones, (K0), qrow, lg, m2, l_run, o)

__device__ __forceinline__ void attn_group_pass(const short* Kt, const short* Vt,
                                                const short* __restrict__ Qb,
                                                short* __restrict__ Ob, int bh,
                                                int G, int w, int l, char* lds,
                                                const char* pA, const char* pB,
                                                char* sdst) {
  const int lg = l >> 4, ln = l & 15;
  const int qrow = G * 64 + w * 16 + ln;
  const short* Qp = Qb + ((size_t)bh * SEQ + qrow) * HD;
  const s16x8 qf0 = *(const s16x8*)(Qp + lg * 8);
  const s16x8 qf1 = *(const s16x8*)(Qp + 32 + lg * 8);
  s16x8 ones;
#pragma unroll
  for (int j = 0; j < 8; j++) ones[j] = (short)0x3F80;  // bf16 1.0

  float m2 = -3e38f, l_run = 0.f;
  f32x4 o[4];
#pragma unroll
  for (int i = 0; i < 4; i++) o[i] = f32x4{0.f, 0.f, 0.f, 0.f};

  const int nt = G + 1;  // tiles 0..G; tile G is the masked diagonal
  __builtin_amdgcn_s_barrier();  // prior pass's readers done before overwrite
  stage_tile(Kt, Vt, 0, sdst, 0, w);
  for (int t = 0; t < nt - 1; ++t) {
    stage_tile(Kt, Vt, t + 1, sdst, ((t + 1) % 3) * 16384, w);
    asm volatile("s_waitcnt vmcnt(4)" ::: "memory");  // own tile-t loads done
    __builtin_amdgcn_s_barrier();                     // => all waves' t landed
    __builtin_amdgcn_sched_barrier(0);
    switch (t % 3) {
      case 0: CT(0, false, t * 64); break;
      case 1: CT(16384, false, t * 64); break;
      default: CT(32768, false, t * 64); break;
    }
  }
  asm volatile("s_waitcnt vmcnt(0)" ::: "memory");
  __builtin_amdgcn_s_barrier();
  __builtin_amdgcn_sched_barrier(0);
  switch ((nt - 1) % 3) {
    case 0: CT(0, true, (nt - 1) * 64); break;
    case 1: CT(16384, true, (nt - 1) * 64); break;
    default: CT(32768, true, (nt - 1) * 64); break;
  }

  const float inv = 1.0f / l_run;
  const int bb = bh >> 4, hh = bh & 15;
  const size_t orow = (size_t)(bb * SEQ + qrow) * HID + hh * HD;
#pragma unroll
  for (int mt = 0; mt < 4; mt++) {
    s16x4 ov;
#pragma unroll
    for (int r = 0; r < 4; r++) ov[r] = f2bf(o[mt][r] * inv);
    *(s16x4*)(Ob + orow + mt * 16 + lg * 4) = ov;
  }
}

__global__ __launch_bounds__(256) void attn_kernel(const short* __restrict__ Qb,
                                                   const short* __restrict__ Kg,
                                                   const short* __restrict__ Vg,
                                                   short* __restrict__ Ob) {
  __shared__ char lds[49152];  // 3 buffers x (8KB K + 8KB V)
  // XCD swizzle: XCD k owns 64 consecutive logical blocks (4 heads).
  const int bid = blockIdx.x;
  const int L = (bid & 7) * 64 + (bid >> 3);
  const int bh = L >> 4, g = L & 15;
  const int w = threadIdx.x >> 6, l = threadIdx.x & 63;
  const int lg = l >> 4, ln = l & 15, x = ln & 7;
  const char* pA = lds + ln * 128 + ((lg ^ x) * 16);
  const char* pB = lds + ln * 128 + (((4 + lg) ^ x) * 16);
  char* sdst = lds + ((w < 2) ? 0 : 8192) + (w & 1) * 4096 + l * 16;
  const short* Kt = Kg + (size_t)bh * (SEQ * HD);
  const short* Vt = Vg + (size_t)bh * (SEQ * HD);
  attn_group_pass(Kt, Vt, Qb, Ob, bh, g, w, l, lds, pA, pB, sdst);       // short
  attn_group_pass(Kt, Vt, Qb, Ob, bh, 31 - g, w, l, lds, pA, pB, sdst);  // long
}

// ---------------- launch ----------------
extern "C" void kernel_launch(void* const* d_in, const int* in_sizes, int n_in,
                              void* d_out, int out_size, void* d_ws,
                              size_t ws_size, hipStream_t stream) {
  const float* X = (const float*)d_in[0];
  // d_in[1] = mask (causal, implemented directly)
  const float* Wq = (const float*)d_in[2];
  const float* bq = (const float*)d_in[3];
  const float* Wk = (const float*)d_in[4];
  const float* bk = (const float*)d_in[5];
  const float* Wv = (const float*)d_in[6];
  const float* bv = (const float*)d_in[7];
  const float* Wo = (const float*)d_in[8];
  const float* bo = (const float*)d_in[9];
  float* out = (float*)d_out;

  char* ws = (char*)d_ws;
  short* Xb = (short*)(ws);                  // 8 MB  [4096][1024]
  short* Wtall = (short*)(ws + (8u << 20));  // 8 MB  (Wq|Wk|Wv|Wo)^T bf16
  short* Qb = (short*)(ws + (16u << 20));    // 8 MB  [32][2048][64] (pre-scaled)
  short* Kg = (short*)(ws + (24u << 20));    // 8 MB  [32][32 tiles][64x64 image]
  short* Vg = (short*)(ws + (32u << 20));    // 8 MB  [32][32 tiles][64x64 image]
  short* Ob = (short*)(ws + (40u << 20));    // 8 MB  [4096][1024]
  short* Wto = Wtall + (3u << 20);

  prep_kernel<<<dim3(32, 32, 5), 256, 0, stream>>>(X, Wq, Wk, Wv, Wo, Xb, Wtall);

  gemm_bf16<0, 4><<<dim3(24, 32), 256, 0, stream>>>(Xb, Wtall, bq, bk, bv, Qb,
                                                    Kg, Vg, nullptr);
  attn_kernel<<<512, 256, 0, stream>>>(Qb, Kg, Vg, Ob);
  gemm_bf16<1, 2><<<dim3(8, 64), 256, 0, stream>>>(Ob, Wto, bo, nullptr, nullptr,
                                                   nullptr, nullptr, nullptr,
                                                   out);
}

// Round 11
// 218.107 us; speedup vs baseline: 1.0062x; 1.0062x over previous
//
#include <hip/hip_runtime.h>
#include <stdint.h>

#define HID 1024
#define SEQ 2048
#define NB 2
#define NH 16
#define HD 64
#define MROWS 4096  // NB*SEQ

typedef float f32x4 __attribute__((ext_vector_type(4)));
typedef short s16x4 __attribute__((ext_vector_type(4)));
typedef short s16x8 __attribute__((ext_vector_type(8)));
typedef uint32_t u32x4 __attribute__((ext_vector_type(4)));

#define MFMA16(a, b, c) __builtin_amdgcn_mfma_f32_16x16x32_bf16((a), (b), (c), 0, 0, 0)

#define GLOAD_LDS16(gp, lp)                                                    \
  __builtin_amdgcn_global_load_lds(                                            \
      (const __attribute__((address_space(1))) unsigned int*)(gp),             \
      (__attribute__((address_space(3))) unsigned int*)(lp), 16, 0, 0)

__device__ __forceinline__ short f2bf(float x) {
  uint32_t u = __builtin_bit_cast(uint32_t, x);
  u += 0x7fffu + ((u >> 16) & 1u);
  return (short)(u >> 16);
}

__device__ __forceinline__ uint32_t cvtpk(float lo, float hi) {
  uint32_t r;
  asm("v_cvt_pk_bf16_f32 %0, %1, %2" : "=v"(r) : "v"(lo), "v"(hi));
  return r;
}

// -------- merged prep: z<4 -> transpose-cast W_z; z==4 -> cast X --------
__global__ __launch_bounds__(256) void prep_kernel(
    const float* __restrict__ X, const float* __restrict__ w0,
    const float* __restrict__ w1, const float* __restrict__ w2,
    const float* __restrict__ w3, short* __restrict__ Xb,
    short* __restrict__ Wtall) {
  const int z = blockIdx.z;
  if (z == 4) {  // cast X: 16 elems/thread
    const size_t i = ((size_t)blockIdx.y * 32 + blockIdx.x) * 256 + threadIdx.x;
    const float* s = X + i * 16;
    short* d = Xb + i * 16;
#pragma unroll
    for (int h = 0; h < 2; h++) {
      f32x4 a = *(const f32x4*)(s + h * 8);
      f32x4 b = *(const f32x4*)(s + h * 8 + 4);
      s16x8 o;
      o[0] = f2bf(a[0]); o[1] = f2bf(a[1]); o[2] = f2bf(a[2]); o[3] = f2bf(a[3]);
      o[4] = f2bf(b[0]); o[5] = f2bf(b[1]); o[6] = f2bf(b[2]); o[7] = f2bf(b[3]);
      *(s16x8*)(d + h * 8) = o;
    }
    return;
  }
  __shared__ float t[32][33];
  const float* src = (z == 0) ? w0 : (z == 1) ? w1 : (z == 2) ? w2 : w3;
  short* dst = Wtall + ((size_t)z << 20);
  const int tx = threadIdx.x & 31, ty = threadIdx.x >> 5;
  const int r0 = blockIdx.y * 32, c0 = blockIdx.x * 32;
#pragma unroll
  for (int i = 0; i < 4; i++)
    t[ty + i * 8][tx] = src[(size_t)(r0 + ty + i * 8) * HID + c0 + tx];
  __syncthreads();
#pragma unroll
  for (int i = 0; i < 4; i++)
    dst[(size_t)(c0 + ty + i * 8) * HID + r0 + tx] = f2bf(t[tx][ty + i * 8]);
}

// ---------------- bf16 GEMM: C = A[M][1024] * Bt[N][1024]^T ----------------
// Tile (32*MI)x128, BK=32, 4 waves (2x2), 16x16x32 MFMA.
// DEPTH-2 pipeline, 4 LDS buffers: stage(kt+2) -> vmcnt(2*NLD) -> barrier ->
// compute(kt). stage(kt+2) overwrites buf[(kt-2)&3]: its readers are compute
// kt-2 (>=2 barriers past) and kt+2 (future) -> single barrier per tile safe.
// EPI 0 (MI=4): QKV epilogue: bias + scatter; Q pre-scaled by 0.125*log2(e).
// EPI 1: proj epilogue (bias + f32 out [m][1024])
template <int EPI, int MI>
__global__ __launch_bounds__(256) void gemm_bf16(
    const short* __restrict__ A, const short* __restrict__ Bt,
    const float* __restrict__ b0, const float* __restrict__ b1,
    const float* __restrict__ b2, short* __restrict__ Qb, short* __restrict__ Kg,
    short* __restrict__ Vg, float* __restrict__ Out) {
  __shared__ char lds[4][MI * 2048 + 8192];  // 4buf x (A [32*MI][32], B [128][32])
  const int tid = threadIdx.x;
  const int w = tid >> 6, l = tid & 63, lg = l >> 4, ln = l & 15;
  const int wm = w >> 1, wn = w & 1;
  const int m0 = blockIdx.y * (32 * MI), n0 = blockIdx.x * 128;

  f32x4 acc[MI][4];
#pragma unroll
  for (int i = 0; i < MI; i++)
#pragma unroll
    for (int j = 0; j < 4; j++) acc[i][j] = f32x4{0.f, 0.f, 0.f, 0.f};

  auto stage = [&](int buf, int k0) {
#pragma unroll
    for (int i = 0; i < MI / 2; i++) {  // A: MI*128 16B-chunks
      const int c = i * 256 + tid;
      const int row = c >> 2;
      const int cs = (c & 3) ^ (row & 3);  // source-side XOR swizzle
      GLOAD_LDS16(A + (size_t)(m0 + row) * 1024 + k0 + cs * 8,
                  lds[buf] + c * 16);
    }
#pragma unroll
    for (int i = 0; i < 2; i++) {  // B: 512 chunks
      const int c = i * 256 + tid;
      const int row = c >> 2;
      const int cs = (c & 3) ^ (row & 3);
      GLOAD_LDS16(Bt + (size_t)(n0 + row) * 1024 + k0 + cs * 8,
                  lds[buf] + MI * 2048 + c * 16);
    }
  };

  stage(0, 0);
  stage(1, 32);
  for (int kt = 0; kt < 32; ++kt) {
    if (kt + 2 < 32) {
      stage((kt + 2) & 3, (kt + 2) * 32);  // two stages stay in flight
      if constexpr (MI == 4)
        asm volatile("s_waitcnt vmcnt(8)" ::: "memory");
      else
        asm volatile("s_waitcnt vmcnt(6)" ::: "memory");
    } else if (kt == 30) {
      if constexpr (MI == 4)
        asm volatile("s_waitcnt vmcnt(4)" ::: "memory");
      else
        asm volatile("s_waitcnt vmcnt(3)" ::: "memory");
    } else {
      asm volatile("s_waitcnt vmcnt(0)" ::: "memory");
    }
    __builtin_amdgcn_s_barrier();  // kt tile resident for all waves
    __builtin_amdgcn_sched_barrier(0);

    const char* ldsc = lds[kt & 3];
    s16x8 af[MI], bfr[4];
#pragma unroll
    for (int mi = 0; mi < MI; mi++) {
      const int row = wm * (16 * MI) + mi * 16 + ln;
      af[mi] = *(const s16x8*)(ldsc + row * 64 + ((lg ^ (row & 3)) * 16));
    }
#pragma unroll
    for (int ni = 0; ni < 4; ni++) {
      const int row = wn * 64 + ni * 16 + ln;
      bfr[ni] =
          *(const s16x8*)(ldsc + MI * 2048 + row * 64 + ((lg ^ (row & 3)) * 16));
    }
#pragma unroll
    for (int mi = 0; mi < MI; mi++)
#pragma unroll
      for (int ni = 0; ni < 4; ni++)
        acc[mi][ni] = MFMA16(af[mi], bfr[ni], acc[mi][ni]);
  }

  // epilogue: C/D layout row=(lane>>4)*4+reg, col=lane&15
  const float QSC = 0.18033688011112042f;  // (1/8) * log2(e)
#pragma unroll
  for (int ni = 0; ni < 4; ni++) {
    const int c = n0 + wn * 64 + ni * 16 + ln;
    if (EPI == 0) {
      const int mat = c >> 10, cc = c & 1023, hh = cc >> 6, d = cc & 63;
      const float* bp = (mat == 0) ? b0 : (mat == 1) ? b1 : b2;
      const float bias = bp[cc];
#pragma unroll
      for (int mi = 0; mi < MI; mi++) {
#pragma unroll
        for (int r = 0; r < 4; r++) {
          const int m = m0 + wm * (16 * MI) + mi * 16 + lg * 4 + r;
          const int bb = m >> 11, s = m & 2047;
          const float fv = acc[mi][ni][r] + bias;
          const size_t bh = (size_t)(bb * 16 + hh);
          if (mat == 0) {
            Qb[(bh * SEQ + s) * HD + d] = f2bf(fv * QSC);  // pre-scaled Q
          } else if (mat == 1) {
            const int tile = s >> 6, rr = s & 63;
            Kg[bh * (SEQ * HD) + tile * 4096 + rr * 64 +
               ((((d >> 3) ^ (rr & 7)) << 3) | (d & 7))] = f2bf(fv);
          } else {
            // kappa-permute s within its 32-group (PV frag key order):
            const int sp = (s & ~31) | ((s & 12) << 1) | (((s >> 4) & 1) << 2) |
                           (s & 3);
            const int tile = sp >> 6, kp = sp & 63;
            Vg[bh * (SEQ * HD) + tile * 4096 + d * 64 +
               ((((kp >> 3) ^ (d & 7)) << 3) | (kp & 7))] = f2bf(fv);
          }
        }
      }
    } else {
      const float bias = b0[c];
#pragma unroll
      for (int mi = 0; mi < MI; mi++)
#pragma unroll
        for (int r = 0; r < 4; r++) {
          const int m = m0 + wm * (16 * MI) + mi * 16 + lg * 4 + r;
          Out[(size_t)m * 1024 + c] = acc[mi][ni][r] + bias;
        }
    }
  }
}

// ------------- flash attention (causal), DEPTH-2 LDS pipeline -------------
// 512 blocks (XCD-swizzled), 4 waves/block, 64-row Q group. FOUR 16KB K/V
// buffers: stage(t+2) two tiles ahead; vmcnt(8) = own tile-t loads complete;
// one barrier per tile (overwrite target (t+2)&3 is 2 barriers from any
// reader). Redundant clamped stages keep vmcnt arithmetic uniform; vmcnt(0)
// drain at pass entry. VALU diet: Q pre-scaled (exp2-direct), defer-max,
// ones-MFMA psum, cvt_pk packing, static ds_read offsets via <BUF> switch.

__device__ __forceinline__ void stage_tile(const short* Kt, const short* Vt,
                                           int t, char* sdst, int bufoff, int w) {
  const char* src = (w < 2) ? ((const char*)(Kt + (size_t)t * 4096) + (w & 1) * 4096)
                            : ((const char*)(Vt + (size_t)t * 4096) + (w & 1) * 4096);
  char* dst = sdst + bufoff;
#pragma unroll
  for (int j = 0; j < 4; j++)
    GLOAD_LDS16(src + j * 1024 + ((threadIdx.x & 63) * 16), dst + j * 1024);
}

template <int BUF, bool MASK>
__device__ __forceinline__ void compute_tile(const char* pA, const char* pB,
                                             const s16x8& qf0, const s16x8& qf1,
                                             const s16x8& ones, int k0, int qrow,
                                             int lg, float& m2, float& l_run,
                                             f32x4 o[4]) {
  f32x4 st[4];
  __builtin_amdgcn_s_setprio(1);
#pragma unroll
  for (int mt = 0; mt < 4; mt++) {
    const s16x8 k0f = *(const s16x8*)(pA + BUF + mt * 2048);
    const s16x8 k1f = *(const s16x8*)(pB + BUF + mt * 2048);
    st[mt] = f32x4{0.f, 0.f, 0.f, 0.f};
    st[mt] = MFMA16(k0f, qf0, st[mt]);
    st[mt] = MFMA16(k1f, qf1, st[mt]);
  }
  __builtin_amdgcn_s_setprio(0);
  // V frags (independent of softmax; latency hides under it)
  s16x8 vf[2][4];
#pragma unroll
  for (int vmt = 0; vmt < 4; vmt++) {
    vf[0][vmt] = *(const s16x8*)(pA + BUF + 8192 + vmt * 2048);
    vf[1][vmt] = *(const s16x8*)(pB + BUF + 8192 + vmt * 2048);
  }
  if (MASK) {
#pragma unroll
    for (int mt = 0; mt < 4; mt++)
#pragma unroll
      for (int r = 0; r < 4; r++) {
        const int key = k0 + mt * 16 + lg * 4 + r;
        if (key > qrow) st[mt][r] = -3e38f;
      }
  }
  // max via fused max3 chain
  float pmax = fmaxf(fmaxf(st[0][0], st[0][1]), st[0][2]);
  pmax = fmaxf(fmaxf(pmax, st[0][3]), st[1][0]);
  pmax = fmaxf(fmaxf(pmax, st[1][1]), st[1][2]);
  pmax = fmaxf(fmaxf(pmax, st[1][3]), st[2][0]);
  pmax = fmaxf(fmaxf(pmax, st[2][1]), st[2][2]);
  pmax = fmaxf(fmaxf(pmax, st[2][3]), st[3][0]);
  pmax = fmaxf(fmaxf(pmax, st[3][1]), st[3][2]);
  pmax = fmaxf(pmax, st[3][3]);

  if (!__all(pmax <= m2 + 8.0f)) {  // defer-max: rescale only on real growth
    pmax = fmaxf(pmax, __shfl_xor(pmax, 16));
    pmax = fmaxf(pmax, __shfl_xor(pmax, 32));
    const float m_new = fmaxf(m2, pmax);
    const float corr = exp2f(m2 - m_new);
    l_run *= corr;
#pragma unroll
    for (int i = 0; i < 4; i++) o[i] *= corr;
    m2 = m_new;
  }
#pragma unroll
  for (int mt = 0; mt < 4; mt++)
#pragma unroll
    for (int r = 0; r < 4; r++) st[mt][r] = exp2f(st[mt][r] - m2);

  s16x8 pf[2];
#pragma unroll
  for (int s = 0; s < 2; s++) {
    u32x4 wv;
    wv[0] = cvtpk(st[s * 2][0], st[s * 2][1]);
    wv[1] = cvtpk(st[s * 2][2], st[s * 2][3]);
    wv[2] = cvtpk(st[s * 2 + 1][0], st[s * 2 + 1][1]);
    wv[3] = cvtpk(st[s * 2 + 1][2], st[s * 2 + 1][3]);
    pf[s] = __builtin_bit_cast(s16x8, wv);
  }
  __builtin_amdgcn_s_setprio(1);
  f32x4 ps = f32x4{0.f, 0.f, 0.f, 0.f};
  ps = MFMA16(ones, pf[0], ps);
  ps = MFMA16(ones, pf[1], ps);
#pragma unroll
  for (int s = 0; s < 2; s++)
#pragma unroll
    for (int vmt = 0; vmt < 4; vmt++)
      o[vmt] = MFMA16(vf[s][vmt], pf[s], o[vmt]);
  __builtin_amdgcn_s_setprio(0);
  l_run += ps[0];
}

#define CT(BUF, MASKV, K0)                                                     \
  compute_tile<BUF, MASKV>(pA, pB, qf0, qf1, ones, (K0), qrow, lg, m2, l_run, o)

__device__ __forceinline__ void attn_group_pass(const short* Kt, const short* Vt,
                                                const short* __restrict__ Qb,
                                                short* __restrict__ Ob, int bh,
                                                int G, int w, int l, char* lds,
                                                const char* pA, const char* pB,
                                                char* sdst) {
  const int lg = l >> 4, ln = l & 15;
  const int qrow = G * 64 + w * 16 + ln;
  const short* Qp = Qb + ((size_t)bh * SEQ + qrow) * HD;
  const s16x8 qf0 = *(const s16x8*)(Qp + lg * 8);
  const s16x8 qf1 = *(const s16x8*)(Qp + 32 + lg * 8);
  s16x8 ones;
#pragma unroll
  for (int j = 0; j < 8; j++) ones[j] = (short)0x3F80;  // bf16 1.0

  float m2 = -3e38f, l_run = 0.f;
  f32x4 o[4];
#pragma unroll
  for (int i = 0; i < 4; i++) o[i] = f32x4{0.f, 0.f, 0.f, 0.f};

  const int nt = G + 1;  // tiles 0..G; tile G is the masked diagonal
  asm volatile("s_waitcnt vmcnt(0)" ::: "memory");  // drain prior pass loads
  __builtin_amdgcn_s_barrier();  // prior pass's readers done before overwrite
  stage_tile(Kt, Vt, 0, sdst, 0, w);
  stage_tile(Kt, Vt, (1 < nt) ? 1 : 0, sdst, 16384, w);
  for (int t = 0; t < nt - 1; ++t) {
    const int si = (t + 2 < nt) ? t + 2 : nt - 1;  // clamp: uniform vmcnt math
    stage_tile(Kt, Vt, si, sdst, ((t + 2) & 3) * 16384, w);
    asm volatile("s_waitcnt vmcnt(8)" ::: "memory");  // own tile-t loads done
    __builtin_amdgcn_s_barrier();                     // => all waves' t landed
    __builtin_amdgcn_sched_barrier(0);
    switch (t & 3) {
      case 0: CT(0, false, t * 64); break;
      case 1: CT(16384, false, t * 64); break;
      case 2: CT(32768, false, t * 64); break;
      default: CT(49152, false, t * 64); break;
    }
  }
  asm volatile("s_waitcnt vmcnt(4)" ::: "memory");  // tile nt-1 resident
  __builtin_amdgcn_s_barrier();
  __builtin_amdgcn_sched_barrier(0);
  switch ((nt - 1) & 3) {
    case 0: CT(0, true, (nt - 1) * 64); break;
    case 1: CT(16384, true, (nt - 1) * 64); break;
    case 2: CT(32768, true, (nt - 1) * 64); break;
    default: CT(49152, true, (nt - 1) * 64); break;
  }

  const float inv = 1.0f / l_run;
  const int bb = bh >> 4, hh = bh & 15;
  const size_t orow = (size_t)(bb * SEQ + qrow) * HID + hh * HD;
#pragma unroll
  for (int mt = 0; mt < 4; mt++) {
    s16x4 ov;
#pragma unroll
    for (int r = 0; r < 4; r++) ov[r] = f2bf(o[mt][r] * inv);
    *(s16x4*)(Ob + orow + mt * 16 + lg * 4) = ov;
  }
}

__global__ __launch_bounds__(256) void attn_kernel(const short* __restrict__ Qb,
                                                   const short* __restrict__ Kg,
                                                   const short* __restrict__ Vg,
                                                   short* __restrict__ Ob) {
  __shared__ char lds[65536];  // 4 buffers x (8KB K + 8KB V)
  // XCD swizzle: XCD k owns 64 consecutive logical blocks (4 heads).
  const int bid = blockIdx.x;
  const int L = (bid & 7) * 64 + (bid >> 3);
  const int bh = L >> 4, g = L & 15;
  const int w = threadIdx.x >> 6, l = threadIdx.x & 63;
  const int lg = l >> 4, ln = l & 15, x = ln & 7;
  const char* pA = lds + ln * 128 + ((lg ^ x) * 16);
  const char* pB = lds + ln * 128 + (((4 + lg) ^ x) * 16);
  char* sdst = lds + ((w < 2) ? 0 : 8192) + (w & 1) * 4096 + l * 16;
  const short* Kt = Kg + (size_t)bh * (SEQ * HD);
  const short* Vt = Vg + (size_t)bh * (SEQ * HD);
  attn_group_pass(Kt, Vt, Qb, Ob, bh, g, w, l, lds, pA, pB, sdst);       // short
  attn_group_pass(Kt, Vt, Qb, Ob, bh, 31 - g, w, l, lds, pA, pB, sdst);  // long
}

// ---------------- launch ----------------
extern "C" void kernel_launch(void* const* d_in, const int* in_sizes, int n_in,
                              void* d_out, int out_size, void* d_ws,
                              size_t ws_size, hipStream_t stream) {
  const float* X = (const float*)d_in[0];
  // d_in[1] = mask (causal, implemented directly)
  const float* Wq = (const float*)d_in[2];
  const float* bq = (const float*)d_in[3];
  const float* Wk = (const float*)d_in[4];
  const float* bk = (const float*)d_in[5];
  const float* Wv = (const float*)d_in[6];
  const float* bv = (const float*)d_in[7];
  const float* Wo = (const float*)d_in[8];
  const float* bo = (const float*)d_in[9];
  float* out = (float*)d_out;

  char* ws = (char*)d_ws;
  short* Xb = (short*)(ws);                  // 8 MB  [4096][1024]
  short* Wtall = (short*)(ws + (8u << 20));  // 8 MB  (Wq|Wk|Wv|Wo)^T bf16
  short* Qb = (short*)(ws + (16u << 20));    // 8 MB  [32][2048][64] (pre-scaled)
  short* Kg = (short*)(ws + (24u << 20));    // 8 MB  [32][32 tiles][64x64 image]
  short* Vg = (short*)(ws + (32u << 20));    // 8 MB  [32][32 tiles][64x64 image]
  short* Ob = (short*)(ws + (40u << 20));    // 8 MB  [4096][1024]
  short* Wto = Wtall + (3u << 20);

  prep_kernel<<<dim3(32, 32, 5), 256, 0, stream>>>(X, Wq, Wk, Wv, Wo, Xb, Wtall);

  gemm_bf16<0, 4><<<dim3(24, 32), 256, 0, stream>>>(Xb, Wtall, bq, bk, bv, Qb,
                                                    Kg, Vg, nullptr);
  attn_kernel<<<512, 256, 0, stream>>>(Qb, Kg, Vg, Ob);
  gemm_bf16<1, 2><<<dim3(8, 64), 256, 0, stream>>>(Ob, Wto, bo, nullptr, nullptr,
                                                   nullptr, nullptr, nullptr,
                                                   out);
}